// Round 1
// baseline (2315.667 us; speedup 1.0000x reference)
//
#include <hip/hip_runtime.h>
#include <cstdint>
#include <cstddef>

#define DEV __device__ __forceinline__

constexpr int D = 128;
constexpr float MINN  = 1e-15f;
constexpr float MAXN  = 1.0f - 4e-3f;   // (1 - BALL_EPS)/sqrt(c), c=1
constexpr float ACLIP = 1.0f - 1e-7f;

DEV float wave_sum(float v) {
#pragma unroll
  for (int off = 32; off > 0; off >>= 1) v += __shfl_xor(v, off, 64);
  return v;
}

DEV float artanh_clip(float x) {   // x >= 0 in all our uses
  x = fminf(x, ACLIP);
  return 0.5f * logf((1.0f + x) / (1.0f - x));
}

// ---------------------------------------------------------------- utility
__global__ void zero_k(int* p, int n) {
  int i = blockIdx.x * 256 + threadIdx.x;
  if (i < n) p[i] = 0;
}

__global__ void hist_k(const int* __restrict__ dst, int E, int* __restrict__ deg) {
  int i = blockIdx.x * 256 + threadIdx.x;
  if (i < E) atomicAdd(&deg[dst[i]], 1);
}

// exclusive scan, 1024 elements per block (Hillis-Steele in LDS)
__global__ __launch_bounds__(1024) void scan1_k(const int* __restrict__ in,
                                                int* __restrict__ out,
                                                int* __restrict__ bsum, int n) {
  __shared__ int sh[1024];
  int t = threadIdx.x;
  int idx = blockIdx.x * 1024 + t;
  int v = (idx < n) ? in[idx] : 0;
  sh[t] = v;
  __syncthreads();
  for (int o = 1; o < 1024; o <<= 1) {
    int add = (t >= o) ? sh[t - o] : 0;
    __syncthreads();
    sh[t] += add;
    __syncthreads();
  }
  if (idx < n) out[idx] = sh[t] - v;     // exclusive
  if (t == 1023) bsum[blockIdx.x] = sh[t];
}

__global__ void scan2_k(const int* __restrict__ bsum, int* __restrict__ boff, int nb) {
  if (threadIdx.x == 0 && blockIdx.x == 0) {
    int run = 0;
    for (int b = 0; b < nb; ++b) { boff[b] = run; run += bsum[b]; }
  }
}

__global__ void scan3_k(int* __restrict__ off, const int* __restrict__ boff,
                        int* __restrict__ cur, int n, int E) {
  int idx = blockIdx.x * 256 + threadIdx.x;
  if (idx < n) {
    int v = off[idx] + boff[idx >> 10];
    off[idx] = v;
    cur[idx] = v;
  }
  if (idx == 0) off[n] = E;
}

__global__ void fill_k(const int* __restrict__ src, const int* __restrict__ dst,
                       int E, int* __restrict__ cur, int* __restrict__ lst) {
  int i = blockIdx.x * 256 + threadIdx.x;
  if (i < E) {
    int p = atomicAdd(&cur[dst[i]], 1);
    lst[p] = src[i];
  }
}

__global__ void rowsq_k(const float* __restrict__ x, float* __restrict__ out, int n) {
  int lane = threadIdx.x & 63;
  int row = blockIdx.x * 4 + (threadIdx.x >> 6);
  if (row >= n) return;
  const float2 v = *(const float2*)(x + (size_t)row * D + lane * 2);
  float s = wave_sum(v.x * v.x + v.y * v.y);
  if (lane == 0) out[row] = s;
}

// hb = proj(expmap0(b)), hbsq = ||hb||^2.  one wave.
__global__ void bias_k(const float* __restrict__ b, float* __restrict__ hb,
                       float* __restrict__ hbsq, int dim) {
  int lane = threadIdx.x;
  int ne = dim / 64;
  float v[4];
  float ssq = 0.0f;
  for (int e = 0; e < ne; ++e) { v[e] = b[e * 64 + lane]; ssq += v[e] * v[e]; }
  ssq = wave_sum(ssq);
  float nr = sqrtf(ssq);
  float nc = fmaxf(nr, MINN);
  float es = tanhf(nc) / nc;
  float on = es * nr;
  float f = (on > MAXN) ? (MAXN / fmaxf(on, MINN)) : 1.0f;
  float w = es * f;
  float osq = 0.0f;
  for (int e = 0; e < ne; ++e) { v[e] *= w; osq += v[e] * v[e]; hb[e * 64 + lane] = v[e]; }
  osq = wave_sum(osq);
  if (lane == 0) *hbsq = osq;
}

// mean aggregation over CSR bucket; writes mean rows + their rowsumsq.
template <int NF>
__global__ __launch_bounds__(256) void agg_k(
    const float* __restrict__ F0, const float* __restrict__ F1,
    const int* __restrict__ off, const int* __restrict__ lst,
    float* __restrict__ O0, float* __restrict__ O1,
    float* __restrict__ S0, float* __restrict__ S1, int n) {
  int lane = threadIdx.x & 63;
  int row = blockIdx.x * 4 + (threadIdx.x >> 6);
  if (row >= n) return;
  int j0 = off[row], j1 = off[row + 1];
  float a0 = 0, b0 = 0, a1 = 0, b1 = 0;
  int j = j0;
  for (; j + 1 < j1; j += 2) {   // unroll-by-2 for MLP
    int sa = lst[j], sb = lst[j + 1];
    const float2 u0 = *(const float2*)(F0 + (size_t)sa * D + lane * 2);
    const float2 u1 = *(const float2*)(F0 + (size_t)sb * D + lane * 2);
    a0 += u0.x + u1.x; b0 += u0.y + u1.y;
    if (NF == 2) {
      const float2 w0 = *(const float2*)(F1 + (size_t)sa * D + lane * 2);
      const float2 w1 = *(const float2*)(F1 + (size_t)sb * D + lane * 2);
      a1 += w0.x + w1.x; b1 += w0.y + w1.y;
    }
  }
  if (j < j1) {
    int sa = lst[j];
    const float2 u0 = *(const float2*)(F0 + (size_t)sa * D + lane * 2);
    a0 += u0.x; b0 += u0.y;
    if (NF == 2) {
      const float2 w0 = *(const float2*)(F1 + (size_t)sa * D + lane * 2);
      a1 += w0.x; b1 += w0.y;
    }
  }
  float inv = 1.0f / fmaxf((float)(j1 - j0), 1.0f);
  a0 *= inv; b0 *= inv;
  float s = wave_sum(a0 * a0 + b0 * b0);
  *((float2*)(O0 + (size_t)row * D) + lane) = make_float2(a0, b0);
  if (lane == 0) S0[row] = s;
  if (NF == 2) {
    a1 *= inv; b1 *= inv;
    float s1 = wave_sum(a1 * a1 + b1 * b1);
    *((float2*)(O1 + (size_t)row * D) + lane) = make_float2(a1, b1);
    if (lane == 0) S1[row] = s1;
  }
}

// C[M, gridDim.y*64] = concat_s(A_s) @ W^T ; W is [dout, nsrc*128] row-major.
// 64x64 tile, BK=32, fp32 FMA, k-major LDS tiles for float4 fragment reads.
__global__ __launch_bounds__(256) void gemm_k(
    const float* __restrict__ A0, int lda0,
    const float* __restrict__ A1, int lda1,
    const float* __restrict__ A2, int lda2,
    const float* __restrict__ W, int ldw,
    float* __restrict__ C, int ldc, int M, int nsrc) {
  __shared__ float As[32][68];
  __shared__ float Ws[32][68];
  const int t = threadIdx.x;
  const int tx = t & 15, ty = t >> 4;
  const int brow = blockIdx.x * 64;
  const int bcol = blockIdx.y * 64;
  const int arow = t >> 3;   // 0..31
  const int akq = t & 7;     // 0..7
  float acc[4][4] = {};
  const int nk = nsrc * 4;
  for (int kc = 0; kc < nk; ++kc) {
    const int s = kc >> 2;
    const int koff = (kc & 3) * 32;
    const float* Ap = (s == 0) ? A0 : ((s == 1) ? A1 : A2);
    const int lda = (s == 0) ? lda0 : ((s == 1) ? lda1 : lda2);
#pragma unroll
    for (int h = 0; h < 2; ++h) {
      int r = arow + h * 32;
      int rg = brow + r;
      float4 av = make_float4(0, 0, 0, 0);
      if (rg < M) av = *(const float4*)(Ap + (size_t)rg * lda + koff + akq * 4);
      As[akq * 4 + 0][r] = av.x; As[akq * 4 + 1][r] = av.y;
      As[akq * 4 + 2][r] = av.z; As[akq * 4 + 3][r] = av.w;
      int cg = bcol + r;
      float4 wv = *(const float4*)(W + (size_t)cg * ldw + s * 128 + koff + akq * 4);
      Ws[akq * 4 + 0][r] = wv.x; Ws[akq * 4 + 1][r] = wv.y;
      Ws[akq * 4 + 2][r] = wv.z; Ws[akq * 4 + 3][r] = wv.w;
    }
    __syncthreads();
#pragma unroll
    for (int kk = 0; kk < 32; ++kk) {
      float a[4], b[4];
      *(float4*)a = *(const float4*)&As[kk][ty * 4];
      *(float4*)b = *(const float4*)&Ws[kk][tx * 4];
#pragma unroll
      for (int i = 0; i < 4; ++i)
#pragma unroll
        for (int jj = 0; jj < 4; ++jj) acc[i][jj] = fmaf(a[i], b[jj], acc[i][jj]);
    }
    __syncthreads();
  }
#pragma unroll
  for (int i = 0; i < 4; ++i) {
    int rg = brow + ty * 4 + i;
    if (rg < M) {
      float4 o = make_float4(acc[i][0], acc[i][1], acc[i][2], acc[i][3]);
      *(float4*)(C + (size_t)rg * ldc + bcol + tx * 4) = o;
    }
  }
}

// Full hyperbolic epilogue for one row (wave per row):
// res=mobius_matvec scaling of mx; proj; mobius_add(hb); proj; logmap0; relu;
// expmap0; proj.  xn^2 = xs0[row] (+xs1 +xs2).
template <int EL>
__global__ __launch_bounds__(256) void epi_k(
    const float* __restrict__ mx, int ldmx,
    const float* __restrict__ xs0, const float* __restrict__ xs1,
    const float* __restrict__ xs2,
    const float* __restrict__ hb, const float* __restrict__ hbsq_p,
    float* __restrict__ outp, int ldout,
    float* __restrict__ hsq_out, int n) {
  int lane = threadIdx.x & 63;
  int row = blockIdx.x * 4 + (threadIdx.x >> 6);
  if (row >= n) return;
  float v[EL], hbv[EL];
  const float* mrow = mx + (size_t)row * ldmx;
  float ssq = 0.0f;
#pragma unroll
  for (int e = 0; e < EL; ++e) {
    v[e] = mrow[e * 64 + lane];
    ssq += v[e] * v[e];
    hbv[e] = hb[e * 64 + lane];
  }
  ssq = wave_sum(ssq);
  float mxn_raw = sqrtf(ssq);
  float xnsq = xs0[row];
  if (xs1) xnsq += xs1[row];
  if (xs2) xnsq += xs2[row];
  float xn = fmaxf(sqrtf(xnsq), MINN);
  float mxn = fmaxf(mxn_raw, MINN);
  float scal = tanhf(mxn / xn * artanh_clip(xn)) / mxn;   // res = scal*mx
  float rn_raw = scal * mxn_raw;                          // ||res||
  // proj(res)
  if (rn_raw > MAXN) { scal *= MAXN / fmaxf(rn_raw, MINN); rn_raw = MAXN; }
  float xy = 0.0f;
#pragma unroll
  for (int e = 0; e < EL; ++e) { v[e] *= scal; xy += v[e] * hbv[e]; }
  xy = wave_sum(xy);
  float x2 = rn_raw * rn_raw;
  float y2 = *hbsq_p;
  float den = fmaxf(1.0f + 2.0f * xy + x2 * y2, MINN);
  float ax = (1.0f + 2.0f * xy + y2) / den;
  float ay = (1.0f - x2) / den;
  float psq = 0.0f;
#pragma unroll
  for (int e = 0; e < EL; ++e) { v[e] = ax * v[e] + ay * hbv[e]; psq += v[e] * v[e]; }
  psq = wave_sum(psq);
  float pn_raw = sqrtf(psq);
  float f2 = (pn_raw > MAXN) ? (MAXN / fmaxf(pn_raw, MINN)) : 1.0f;
  pn_raw = fminf(pn_raw, MAXN);
  float pn = fmaxf(pn_raw, MINN);
  float la = artanh_clip(pn) / pn * f2;   // includes proj scale
  float tsq = 0.0f;
#pragma unroll
  for (int e = 0; e < EL; ++e) { v[e] = fmaxf(la * v[e], 0.0f); tsq += v[e] * v[e]; }
  tsq = wave_sum(tsq);
  float tn_raw = sqrtf(tsq);
  float tnc = fmaxf(tn_raw, MINN);
  float es = tanhf(tnc) / tnc;
  float on_raw = es * tn_raw;
  float f3 = (on_raw > MAXN) ? (MAXN / fmaxf(on_raw, MINN)) : 1.0f;
  float w = es * f3;
  float osq = 0.0f;
  float* orow = outp + (size_t)row * ldout;
#pragma unroll
  for (int e = 0; e < EL; ++e) { v[e] *= w; osq += v[e] * v[e]; orow[e * 64 + lane] = v[e]; }
  if (hsq_out) {
    osq = wave_sum(osq);
    if (lane == 0) hsq_out[row] = osq;
  }
}

__global__ void xcopy_k(const float4* __restrict__ x4, float4* __restrict__ out4, int n) {
  int gid = blockIdx.x * 256 + threadIdx.x;
  if (gid < n * 32) {
    int i = gid >> 5, q = gid & 31;
    out4[(size_t)i * 96 + 64 + q] = x4[(size_t)i * 32 + q];
  }
}

// ---------------------------------------------------------------- launcher
extern "C" void kernel_launch(void* const* d_in, const int* in_sizes, int n_in,
                              void* d_out, int out_size, void* d_ws, size_t ws_size,
                              hipStream_t stream) {
  const float* x = (const float*)d_in[0];
  const int* src_pos = (const int*)d_in[1];
  const int* dst_pos = (const int*)d_in[2];
  const int* src_neg = (const int*)d_in[3];
  const int* dst_neg = (const int*)d_in[4];
  const float* W1b = (const float*)d_in[5];
  const float* b1b = (const float*)d_in[6];
  const float* W1h = (const float*)d_in[7];
  const float* b1h = (const float*)d_in[8];
  const float* W2b = (const float*)d_in[9];
  const float* b2b = (const float*)d_in[10];
  const float* W2h = (const float*)d_in[11];
  const float* b2h = (const float*)d_in[12];
  const float* W3b = (const float*)d_in[13];
  const float* b3b = (const float*)d_in[14];
  const float* W3h = (const float*)d_in[15];
  const float* b3h = (const float*)d_in[16];

  const int N = in_sizes[0] / D;   // 100000
  const int E = in_sizes[1];       // 1600000

  // ---- workspace layout (ints then floats) ----
  int* iw = (int*)d_ws;
  size_t io = 0;
  int* degi_p = iw + io; io += N;
  int* degi_n = iw + io; io += N;
  int* off_p = iw + io;  io += N + 1;
  int* off_n = iw + io;  io += N + 1;
  int* cur_p = iw + io;  io += N;
  int* cur_n = iw + io;  io += N;
  int* bsum_p = iw + io; io += 128;
  int* boff_p = iw + io; io += 128;
  int* bsum_n = iw + io; io += 128;
  int* boff_n = iw + io; io += 128;
  int* lst_p = iw + io;  io += E;
  int* lst_n = iw + io;  io += E;
  io = (io + 63) & ~(size_t)63;

  float* fw = (float*)(iw + io);
  size_t fo = 0;
  float* xsq = fw + fo;    fo += N;
  float* hsq_b1 = fw + fo; fo += N;
  float* hsq_n1 = fw + fo; fo += N;
  float* hsq_b2 = fw + fo; fo += N;
  float* hsq_n2 = fw + fo; fo += N;
  float* ssq_p1 = fw + fo; fo += N;
  float* ssq_n1 = fw + fo; fo += N;
  float* ssq_pp = fw + fo; fo += N;
  float* ssq_np = fw + fo; fo += N;
  float* ssq_nn = fw + fo; fo += N;
  float* ssq_bn = fw + fo; fo += N;
  float* hbase = fw + fo;  fo += 1056;   // 6 bias vecs (128,128,256,256,128,128) + 6 scalars
  fo = (fo + 31) & ~(size_t)31;
  float* slot = fw + fo;
  const size_t NS = (size_t)N * D;
  float* s0 = slot;
  float* s1 = slot + NS;
  float* s2 = slot + 2 * NS;
  float* s3 = slot + 3 * NS;
  float* s4 = slot + 4 * NS;   // s4..s5 hold [N,256]
  float* outf = (float*)d_out;
  float* outA = outf;          // scratch in d_out (dead before final writes)
  float* outB = outf + NS;

  float* hb1b = hbase + 0;
  float* hb1h = hbase + 128;
  float* hb2b = hbase + 256;
  float* hb2h = hbase + 512;
  float* hb3b = hbase + 768;
  float* hb3h = hbase + 896;
  float* hbsq = hbase + 1024;

  const int nb = (N + 1023) / 1024;
  const int grow = (N + 3) / 4;        // wave-per-row kernels
  const int geb = (E + 255) / 256;
  dim3 g1((N + 63) / 64, 2);           // dout=128
  dim3 g2((N + 63) / 64, 4);           // dout=256

  // ---- CSR build for both edge sets ----
  zero_k<<<(2 * N + 255) / 256, 256, 0, stream>>>(degi_p, 2 * N);
  hist_k<<<geb, 256, 0, stream>>>(dst_pos, E, degi_p);
  hist_k<<<geb, 256, 0, stream>>>(dst_neg, E, degi_n);
  scan1_k<<<nb, 1024, 0, stream>>>(degi_p, off_p, bsum_p, N);
  scan1_k<<<nb, 1024, 0, stream>>>(degi_n, off_n, bsum_n, N);
  scan2_k<<<1, 64, 0, stream>>>(bsum_p, boff_p, nb);
  scan2_k<<<1, 64, 0, stream>>>(bsum_n, boff_n, nb);
  scan3_k<<<(N + 255) / 256, 256, 0, stream>>>(off_p, boff_p, cur_p, N, E);
  scan3_k<<<(N + 255) / 256, 256, 0, stream>>>(off_n, boff_n, cur_n, N, E);
  fill_k<<<geb, 256, 0, stream>>>(src_pos, dst_pos, E, cur_p, lst_p);
  fill_k<<<geb, 256, 0, stream>>>(src_neg, dst_neg, E, cur_n, lst_n);

  // ---- constants ----
  rowsq_k<<<grow, 256, 0, stream>>>(x, xsq, N);
  bias_k<<<1, 64, 0, stream>>>(b1b, hb1b, hbsq + 0, 128);
  bias_k<<<1, 64, 0, stream>>>(b1h, hb1h, hbsq + 1, 128);
  bias_k<<<1, 64, 0, stream>>>(b2b, hb2b, hbsq + 2, 256);
  bias_k<<<1, 64, 0, stream>>>(b2h, hb2h, hbsq + 3, 256);
  bias_k<<<1, 64, 0, stream>>>(b3b, hb3b, hbsq + 4, 128);
  bias_k<<<1, 64, 0, stream>>>(b3h, hb3h, hbsq + 5, 128);

  // ---- layer 1 ----
  agg_k<1><<<grow, 256, 0, stream>>>(x, nullptr, off_p, lst_p, s0, nullptr, ssq_p1, nullptr, N);
  agg_k<1><<<grow, 256, 0, stream>>>(x, nullptr, off_n, lst_n, s1, nullptr, ssq_n1, nullptr, N);
  gemm_k<<<g1, 256, 0, stream>>>(s0, D, x, D, nullptr, 0, W1b, 2 * D, s2, D, N, 2);
  gemm_k<<<g1, 256, 0, stream>>>(s1, D, x, D, nullptr, 0, W1h, 2 * D, s3, D, N, 2);
  epi_k<2><<<grow, 256, 0, stream>>>(s2, D, ssq_p1, xsq, nullptr, hb1b, hbsq + 0, s2, D, hsq_b1, N);
  epi_k<2><<<grow, 256, 0, stream>>>(s3, D, ssq_n1, xsq, nullptr, hb1h, hbsq + 1, s3, D, hsq_n1, N);

  // ---- layer 2 aggregations (s2=h_b1, s3=h_n1) ----
  agg_k<2><<<grow, 256, 0, stream>>>(s2, s3, off_p, lst_p, s0, outA, ssq_pp, ssq_np, N);
  agg_k<2><<<grow, 256, 0, stream>>>(s3, s2, off_n, lst_n, s1, outB, ssq_nn, ssq_bn, N);
  // u2b = [aggP(h_b1)=s0, aggN(h_n1)=s1, h_b1=s2]
  gemm_k<<<g2, 256, 0, stream>>>(s0, D, s1, D, s2, D, W2b, 3 * D, s4, 2 * D, N, 3);
  // u2n = [aggP(h_n1)=outA, aggN(h_b1)=outB, h_n1=s3] ; C -> s0..s1 (now dead)
  gemm_k<<<g2, 256, 0, stream>>>(outA, D, outB, D, s3, D, W2h, 3 * D, s0, 2 * D, N, 3);
  epi_k<4><<<grow, 256, 0, stream>>>(s4, 2 * D, ssq_pp, ssq_nn, hsq_b1, hb2b, hbsq + 2, s4, 2 * D, hsq_b2, N);
  epi_k<4><<<grow, 256, 0, stream>>>(s0, 2 * D, ssq_np, ssq_bn, hsq_n1, hb2h, hbsq + 3, s0, 2 * D, hsq_n2, N);

  // ---- layer 3 (h_b2 = s4..s5 [N,256], h_n2 = s0..s1 [N,256]) ----
  gemm_k<<<g1, 256, 0, stream>>>(s4, 2 * D, s4 + 128, 2 * D, nullptr, 0, W3b, 2 * D, s2, D, N, 2);
  gemm_k<<<g1, 256, 0, stream>>>(s0, 2 * D, s0 + 128, 2 * D, nullptr, 0, W3h, 2 * D, s3, D, N, 2);
  epi_k<2><<<grow, 256, 0, stream>>>(s2, D, hsq_b2, nullptr, nullptr, hb3b, hbsq + 4, outf, 3 * D, nullptr, N);
  epi_k<2><<<grow, 256, 0, stream>>>(s3, D, hsq_n2, nullptr, nullptr, hb3h, hbsq + 5, outf + D, 3 * D, nullptr, N);
  xcopy_k<<<(N * 32 + 255) / 256, 256, 0, stream>>>((const float4*)x, (float4*)d_out, N);
}

// Round 2
// 1451.138 us; speedup vs baseline: 1.5958x; 1.5958x over previous
//
#include <hip/hip_runtime.h>
#include <cstdint>
#include <cstddef>

#define DEV __device__ __forceinline__

typedef unsigned int uint32;
typedef unsigned short ushort16;
typedef __bf16 bfx8 __attribute__((ext_vector_type(8)));
typedef float f32x4 __attribute__((ext_vector_type(4)));

constexpr int D = 128;
constexpr float MINN  = 1e-15f;
constexpr float MAXN  = 1.0f - 4e-3f;   // (1 - BALL_EPS)/sqrt(c), c=1
constexpr float ACLIP = 1.0f - 1e-7f;

DEV float wave_sum(float v) {
#pragma unroll
  for (int off = 32; off > 0; off >>= 1) v += __shfl_xor(v, off, 64);
  return v;
}

DEV float artanh_clip(float x) {   // x >= 0 in all our uses
  x = fminf(x, ACLIP);
  return 0.5f * logf((1.0f + x) / (1.0f - x));
}

DEV ushort16 f2b(float f) {        // fp32 -> bf16 RNE
  uint32 u = __float_as_uint(f);
  u += 0x7fffu + ((u >> 16) & 1u);
  return (ushort16)(u >> 16);
}
DEV float b2f_lo(uint32 v) { return __uint_as_float(v << 16); }
DEV float b2f_hi(uint32 v) { return __uint_as_float(v & 0xffff0000u); }

// ---------------------------------------------------------------- utility
__global__ void zero_k(int* p, int n) {
  int i = blockIdx.x * 256 + threadIdx.x;
  if (i < n) p[i] = 0;
}

__global__ void cvt_k(const float* __restrict__ in, ushort16* __restrict__ out, int n) {
  int i = blockIdx.x * 256 + threadIdx.x;
  if (i < n) out[i] = f2b(in[i]);
}

__global__ void hist_k(const int* __restrict__ dst, int E, int* __restrict__ deg) {
  int i = blockIdx.x * 256 + threadIdx.x;
  if (i < E) atomicAdd(&deg[dst[i]], 1);
}

__global__ __launch_bounds__(1024) void scan1_k(const int* __restrict__ in,
                                                int* __restrict__ out,
                                                int* __restrict__ bsum, int n) {
  __shared__ int sh[1024];
  int t = threadIdx.x;
  int idx = blockIdx.x * 1024 + t;
  int v = (idx < n) ? in[idx] : 0;
  sh[t] = v;
  __syncthreads();
  for (int o = 1; o < 1024; o <<= 1) {
    int add = (t >= o) ? sh[t - o] : 0;
    __syncthreads();
    sh[t] += add;
    __syncthreads();
  }
  if (idx < n) out[idx] = sh[t] - v;     // exclusive
  if (t == 1023) bsum[blockIdx.x] = sh[t];
}

__global__ void scan2_k(const int* __restrict__ bsum, int* __restrict__ boff, int nb) {
  if (threadIdx.x == 0 && blockIdx.x == 0) {
    int run = 0;
    for (int b = 0; b < nb; ++b) { boff[b] = run; run += bsum[b]; }
  }
}

__global__ void scan3_k(int* __restrict__ off, const int* __restrict__ boff,
                        int* __restrict__ cur, int n, int E) {
  int idx = blockIdx.x * 256 + threadIdx.x;
  if (idx < n) {
    int v = off[idx] + boff[idx >> 10];
    off[idx] = v;
    cur[idx] = v;
  }
  if (idx == 0) off[n] = E;
}

__global__ void fill_k(const int* __restrict__ src, const int* __restrict__ dst,
                       int E, int* __restrict__ cur, int* __restrict__ lst) {
  int i = blockIdx.x * 256 + threadIdx.x;
  if (i < E) {
    int p = atomicAdd(&cur[dst[i]], 1);
    lst[p] = src[i];
  }
}

// x -> xsq (rowsumsq) + bf16 copy
__global__ void rowsq_k(const float* __restrict__ x, float* __restrict__ out,
                        ushort16* __restrict__ xb, int n) {
  int lane = threadIdx.x & 63;
  int row = blockIdx.x * 4 + (threadIdx.x >> 6);
  if (row >= n) return;
  const float2 v = *(const float2*)(x + (size_t)row * D + lane * 2);
  uint32 pk = (uint32)f2b(v.x) | ((uint32)f2b(v.y) << 16);
  *(uint32*)(xb + (size_t)row * D + lane * 2) = pk;
  float s = wave_sum(v.x * v.x + v.y * v.y);
  if (lane == 0) out[row] = s;
}

// hb = proj(expmap0(b)), hbsq = ||hb||^2.  one wave.
__global__ void bias_k(const float* __restrict__ b, float* __restrict__ hb,
                       float* __restrict__ hbsq, int dim) {
  int lane = threadIdx.x;
  int ne = dim / 64;
  float v[4];
  float ssq = 0.0f;
  for (int e = 0; e < ne; ++e) { v[e] = b[e * 64 + lane]; ssq += v[e] * v[e]; }
  ssq = wave_sum(ssq);
  float nr = sqrtf(ssq);
  float nc = fmaxf(nr, MINN);
  float es = tanhf(nc) / nc;
  float on = es * nr;
  float f = (on > MAXN) ? (MAXN / fmaxf(on, MINN)) : 1.0f;
  float w = es * f;
  float osq = 0.0f;
  for (int e = 0; e < ne; ++e) { v[e] *= w; osq += v[e] * v[e]; hb[e * 64 + lane] = v[e]; }
  osq = wave_sum(osq);
  if (lane == 0) *hbsq = osq;
}

// mean aggregation over CSR bucket (bf16 in, bf16 out + fp32 rowsumsq of mean)
template <int NF>
__global__ __launch_bounds__(256) void agg_k(
    const ushort16* __restrict__ F0, const ushort16* __restrict__ F1,
    const int* __restrict__ off, const int* __restrict__ lst,
    ushort16* __restrict__ O0, ushort16* __restrict__ O1,
    float* __restrict__ S0, float* __restrict__ S1, int n) {
  int lane = threadIdx.x & 63;
  int row = blockIdx.x * 4 + (threadIdx.x >> 6);
  if (row >= n) return;
  int j0 = off[row], j1 = off[row + 1];
  float a0 = 0, b0 = 0, a1 = 0, b1 = 0;
  int j = j0;
  for (; j + 1 < j1; j += 2) {
    int sa = lst[j], sb = lst[j + 1];
    uint32 u0 = *(const uint32*)(F0 + (size_t)sa * D + lane * 2);
    uint32 u1 = *(const uint32*)(F0 + (size_t)sb * D + lane * 2);
    a0 += b2f_lo(u0) + b2f_lo(u1); b0 += b2f_hi(u0) + b2f_hi(u1);
    if (NF == 2) {
      uint32 w0 = *(const uint32*)(F1 + (size_t)sa * D + lane * 2);
      uint32 w1 = *(const uint32*)(F1 + (size_t)sb * D + lane * 2);
      a1 += b2f_lo(w0) + b2f_lo(w1); b1 += b2f_hi(w0) + b2f_hi(w1);
    }
  }
  if (j < j1) {
    int sa = lst[j];
    uint32 u0 = *(const uint32*)(F0 + (size_t)sa * D + lane * 2);
    a0 += b2f_lo(u0); b0 += b2f_hi(u0);
    if (NF == 2) {
      uint32 w0 = *(const uint32*)(F1 + (size_t)sa * D + lane * 2);
      a1 += b2f_lo(w0); b1 += b2f_hi(w0);
    }
  }
  float inv = 1.0f / fmaxf((float)(j1 - j0), 1.0f);
  a0 *= inv; b0 *= inv;
  float s = wave_sum(a0 * a0 + b0 * b0);
  *(uint32*)(O0 + (size_t)row * D + lane * 2) = (uint32)f2b(a0) | ((uint32)f2b(b0) << 16);
  if (lane == 0) S0[row] = s;
  if (NF == 2) {
    a1 *= inv; b1 *= inv;
    float s1 = wave_sum(a1 * a1 + b1 * b1);
    *(uint32*)(O1 + (size_t)row * D + lane * 2) = (uint32)f2b(a1) | ((uint32)f2b(b1) << 16);
    if (lane == 0) S1[row] = s1;
  }
}

// ------------------------------------------------ bf16 MFMA GEMM
// C[M, grid.y*64] = concat_c(chunks of 64 k-cols) @ W^T, fp32 accum/out.
// Tile 128x64, BK=64, 4 waves (2x2 of 64x32), 16x16x32 MFMA, XOR-swizzled LDS.
struct GSrc {
  const ushort16* p[6];
  int lda[6];
  int ko[6];
};

__global__ __launch_bounds__(256) void gemm_bf_k(
    GSrc ga, int nchunk, const ushort16* __restrict__ W, int ldw,
    float* __restrict__ C, int ldc, int M) {
  __shared__ ushort16 As[128 * 64];
  __shared__ ushort16 Bs[64 * 64];
  const int t = threadIdx.x;
  const int brow = blockIdx.x * 128;
  const int bcol = blockIdx.y * 64;
  const int l = t & 63;
  const int w = t >> 6;
  const int wr = w >> 1, wc = w & 1;
  const int sr = t >> 3;   // 0..31
  const int sc = t & 7;    // 16B unit
  f32x4 acc[4][2] = {};
  for (int c = 0; c < nchunk; ++c) {
    const ushort16* S = ga.p[c];
    const int lda = ga.lda[c];
    const int ko = ga.ko[c];
#pragma unroll
    for (int h = 0; h < 4; ++h) {       // A: 128 rows x 64 k
      int row = sr + h * 32;
      int gr = brow + row;
      uint4 v = make_uint4(0, 0, 0, 0);
      if (gr < M) v = *(const uint4*)(S + (size_t)gr * lda + ko + sc * 8);
      *(uint4*)((char*)As + row * 128 + ((sc * 16) ^ ((row & 7) << 4))) = v;
    }
#pragma unroll
    for (int h = 0; h < 2; ++h) {       // B: 64 outcols x 64 k
      int u = t + h * 256;
      int row = u >> 3;
      int cc = u & 7;
      uint4 v = *(const uint4*)(W + (size_t)(bcol + row) * ldw + c * 64 + cc * 8);
      *(uint4*)((char*)Bs + row * 128 + ((cc * 16) ^ ((row & 7) << 4))) = v;
    }
    __syncthreads();
#pragma unroll
    for (int ks = 0; ks < 2; ++ks) {
      const int kb = ks * 64 + (l >> 4) * 16;   // byte offset of this lane's 8 bf16
      bfx8 a[4], b[2];
#pragma unroll
      for (int i = 0; i < 4; ++i) {
        int row = wr * 64 + i * 16 + (l & 15);
        a[i] = *(const bfx8*)((const char*)As + row * 128 + (kb ^ ((row & 7) << 4)));
      }
#pragma unroll
      for (int j = 0; j < 2; ++j) {
        int row = wc * 32 + j * 16 + (l & 15);
        b[j] = *(const bfx8*)((const char*)Bs + row * 128 + (kb ^ ((row & 7) << 4)));
      }
#pragma unroll
      for (int i = 0; i < 4; ++i)
#pragma unroll
        for (int j = 0; j < 2; ++j)
          acc[i][j] = __builtin_amdgcn_mfma_f32_16x16x32_bf16(a[i], b[j], acc[i][j], 0, 0, 0);
    }
    __syncthreads();
  }
#pragma unroll
  for (int i = 0; i < 4; ++i) {
    int r0 = brow + wr * 64 + i * 16 + (l >> 4) * 4;
#pragma unroll
    for (int j = 0; j < 2; ++j) {
      int col = bcol + wc * 32 + j * 16 + (l & 15);
#pragma unroll
      for (int r = 0; r < 4; ++r) {
        int gr = r0 + r;
        if (gr < M) C[(size_t)gr * ldc + col] = acc[i][j][r];
      }
    }
  }
}

// Full hyperbolic epilogue (wave per row); bf16 out (mid layers) or fp32 out (final)
template <int EL>
__global__ __launch_bounds__(256) void epi_k(
    const float* __restrict__ mx, int ldmx,
    const float* __restrict__ xs0, const float* __restrict__ xs1,
    const float* __restrict__ xs2,
    const float* __restrict__ hb, const float* __restrict__ hbsq_p,
    ushort16* __restrict__ outb, int ldob,
    float* __restrict__ outf, int ldof,
    float* __restrict__ hsq_out, int n) {
  int lane = threadIdx.x & 63;
  int row = blockIdx.x * 4 + (threadIdx.x >> 6);
  if (row >= n) return;
  float v[EL], hbv[EL];
  const float* mrow = mx + (size_t)row * ldmx;
  float ssq = 0.0f;
#pragma unroll
  for (int e = 0; e < EL; ++e) {
    v[e] = mrow[e * 64 + lane];
    ssq += v[e] * v[e];
    hbv[e] = hb[e * 64 + lane];
  }
  ssq = wave_sum(ssq);
  float mxn_raw = sqrtf(ssq);
  float xnsq = xs0[row];
  if (xs1) xnsq += xs1[row];
  if (xs2) xnsq += xs2[row];
  float xn = fmaxf(sqrtf(xnsq), MINN);
  float mxn = fmaxf(mxn_raw, MINN);
  float scal = tanhf(mxn / xn * artanh_clip(xn)) / mxn;   // res = scal*mx
  float rn_raw = scal * mxn_raw;
  if (rn_raw > MAXN) { scal *= MAXN / fmaxf(rn_raw, MINN); rn_raw = MAXN; }
  float xy = 0.0f;
#pragma unroll
  for (int e = 0; e < EL; ++e) { v[e] *= scal; xy += v[e] * hbv[e]; }
  xy = wave_sum(xy);
  float x2 = rn_raw * rn_raw;
  float y2 = *hbsq_p;
  float den = fmaxf(1.0f + 2.0f * xy + x2 * y2, MINN);
  float ax = (1.0f + 2.0f * xy + y2) / den;
  float ay = (1.0f - x2) / den;
  float psq = 0.0f;
#pragma unroll
  for (int e = 0; e < EL; ++e) { v[e] = ax * v[e] + ay * hbv[e]; psq += v[e] * v[e]; }
  psq = wave_sum(psq);
  float pn_raw = sqrtf(psq);
  float f2 = (pn_raw > MAXN) ? (MAXN / fmaxf(pn_raw, MINN)) : 1.0f;
  pn_raw = fminf(pn_raw, MAXN);
  float pn = fmaxf(pn_raw, MINN);
  float la = artanh_clip(pn) / pn * f2;
  float tsq = 0.0f;
#pragma unroll
  for (int e = 0; e < EL; ++e) { v[e] = fmaxf(la * v[e], 0.0f); tsq += v[e] * v[e]; }
  tsq = wave_sum(tsq);
  float tn_raw = sqrtf(tsq);
  float tnc = fmaxf(tn_raw, MINN);
  float es = tanhf(tnc) / tnc;
  float on_raw = es * tn_raw;
  float f3 = (on_raw > MAXN) ? (MAXN / fmaxf(on_raw, MINN)) : 1.0f;
  float wsc = es * f3;
  float osq = 0.0f;
#pragma unroll
  for (int e = 0; e < EL; ++e) { v[e] *= wsc; osq += v[e] * v[e]; }
  if (outb) {
    ushort16* orow = outb + (size_t)row * ldob;
#pragma unroll
    for (int e = 0; e < EL; ++e) orow[e * 64 + lane] = f2b(v[e]);
  } else {
    float* orow = outf + (size_t)row * ldof;
#pragma unroll
    for (int e = 0; e < EL; ++e) orow[e * 64 + lane] = v[e];
  }
  if (hsq_out) {
    osq = wave_sum(osq);
    if (lane == 0) hsq_out[row] = osq;
  }
}

__global__ void xcopy_k(const float4* __restrict__ x4, float4* __restrict__ out4, int n) {
  int gid = blockIdx.x * 256 + threadIdx.x;
  if (gid < n * 32) {
    int i = gid >> 5, q = gid & 31;
    out4[(size_t)i * 96 + 64 + q] = x4[(size_t)i * 32 + q];
  }
}

// ---------------------------------------------------------------- launcher
extern "C" void kernel_launch(void* const* d_in, const int* in_sizes, int n_in,
                              void* d_out, int out_size, void* d_ws, size_t ws_size,
                              hipStream_t stream) {
  const float* x = (const float*)d_in[0];
  const int* src_pos = (const int*)d_in[1];
  const int* dst_pos = (const int*)d_in[2];
  const int* src_neg = (const int*)d_in[3];
  const int* dst_neg = (const int*)d_in[4];
  const float* W1b = (const float*)d_in[5];
  const float* b1b = (const float*)d_in[6];
  const float* W1h = (const float*)d_in[7];
  const float* b1h = (const float*)d_in[8];
  const float* W2b = (const float*)d_in[9];
  const float* b2b = (const float*)d_in[10];
  const float* W2h = (const float*)d_in[11];
  const float* b2h = (const float*)d_in[12];
  const float* W3b = (const float*)d_in[13];
  const float* b3b = (const float*)d_in[14];
  const float* W3h = (const float*)d_in[15];
  const float* b3h = (const float*)d_in[16];

  const int N = in_sizes[0] / D;   // 100000
  const int E = in_sizes[1];       // 1600000

  // ---- workspace: ints | fp32 | bf16 ----
  int* iw = (int*)d_ws;
  size_t io = 0;
  int* degi_p = iw + io; io += N;
  int* degi_n = iw + io; io += N;
  int* off_p = iw + io;  io += N + 1;
  int* off_n = iw + io;  io += N + 1;
  int* cur_p = iw + io;  io += N;
  int* cur_n = iw + io;  io += N;
  int* bsum_p = iw + io; io += 128;
  int* boff_p = iw + io; io += 128;
  int* bsum_n = iw + io; io += 128;
  int* boff_n = iw + io; io += 128;
  int* lst_p = iw + io;  io += E;
  int* lst_n = iw + io;  io += E;
  io = (io + 63) & ~(size_t)63;

  float* fw = (float*)(iw + io);
  size_t fo = 0;
  float* xsq = fw + fo;    fo += N;
  float* hsq_b1 = fw + fo; fo += N;
  float* hsq_n1 = fw + fo; fo += N;
  float* hsq_b2 = fw + fo; fo += N;
  float* hsq_n2 = fw + fo; fo += N;
  float* ssq_p1 = fw + fo; fo += N;
  float* ssq_n1 = fw + fo; fo += N;
  float* ssq_pp = fw + fo; fo += N;   // ||A_Pb||^2
  float* ssq_np = fw + fo; fo += N;   // ||A_Pn||^2
  float* ssq_nn = fw + fo; fo += N;   // ||A_Nn||^2
  float* ssq_bn = fw + fo; fo += N;   // ||A_Nb||^2
  float* hbase = fw + fo;  fo += 1056;
  fo = (fo + 31) & ~(size_t)31;
  float* F1 = fw + fo;     fo += (size_t)N * D;   // C slots (F1F2 = one [N,256])
  float* F2 = fw + fo;     fo += (size_t)N * D;
  fo = (fo + 31) & ~(size_t)31;

  ushort16* SB = (ushort16*)(fw + fo);
  const size_t NSB = (size_t)N * D;
  ushort16* S0 = SB;             // xb -> A_Nn -> hb2(lo)
  ushort16* S1 = SB + NSB;       // A_Pb(x) -> A_Pb(h) -> hb2(hi)
  ushort16* S2 = SB + 2 * NSB;   // A_Nn(x)... an1 -> A_Pn -> hn2(lo)
  ushort16* S3 = SB + 3 * NSB;   // hb1 -> hn2(hi)
  ushort16* S4 = SB + 4 * NSB;   // hn1
  ushort16* S5 = SB + 5 * NSB;   // A_Nb
  ushort16* wb1b = SB + 6 * NSB;
  ushort16* wb1h = wb1b + 32768;
  ushort16* wb2b = wb1h + 32768;
  ushort16* wb2h = wb2b + 98304;
  ushort16* wb3b = wb2h + 98304;
  ushort16* wb3h = wb3b + 32768;

  float* outf = (float*)d_out;
  float* C3 = outf;              // d_out as [N,256] fp32 scratch (dead before final writes)

  float* hb1b = hbase + 0;
  float* hb1h = hbase + 128;
  float* hb2b = hbase + 256;
  float* hb2h = hbase + 512;
  float* hb3b = hbase + 768;
  float* hb3h = hbase + 896;
  float* hbsq = hbase + 1024;

  const int nb = (N + 1023) / 1024;
  const int grow = (N + 3) / 4;
  const int geb = (E + 255) / 256;
  const int gmx = (N + 127) / 128;
  dim3 gg1(gmx, 2);   // dout=128
  dim3 gg2(gmx, 4);   // dout=256

  // ---- CSR build ----
  zero_k<<<(2 * N + 255) / 256, 256, 0, stream>>>(degi_p, 2 * N);
  hist_k<<<geb, 256, 0, stream>>>(dst_pos, E, degi_p);
  hist_k<<<geb, 256, 0, stream>>>(dst_neg, E, degi_n);
  scan1_k<<<nb, 1024, 0, stream>>>(degi_p, off_p, bsum_p, N);
  scan1_k<<<nb, 1024, 0, stream>>>(degi_n, off_n, bsum_n, N);
  scan2_k<<<1, 64, 0, stream>>>(bsum_p, boff_p, nb);
  scan2_k<<<1, 64, 0, stream>>>(bsum_n, boff_n, nb);
  scan3_k<<<(N + 255) / 256, 256, 0, stream>>>(off_p, boff_p, cur_p, N, E);
  scan3_k<<<(N + 255) / 256, 256, 0, stream>>>(off_n, boff_n, cur_n, N, E);
  fill_k<<<geb, 256, 0, stream>>>(src_pos, dst_pos, E, cur_p, lst_p);
  fill_k<<<geb, 256, 0, stream>>>(src_neg, dst_neg, E, cur_n, lst_n);

  // ---- constants ----
  rowsq_k<<<grow, 256, 0, stream>>>(x, xsq, S0, N);
  bias_k<<<1, 64, 0, stream>>>(b1b, hb1b, hbsq + 0, 128);
  bias_k<<<1, 64, 0, stream>>>(b1h, hb1h, hbsq + 1, 128);
  bias_k<<<1, 64, 0, stream>>>(b2b, hb2b, hbsq + 2, 256);
  bias_k<<<1, 64, 0, stream>>>(b2h, hb2h, hbsq + 3, 256);
  bias_k<<<1, 64, 0, stream>>>(b3b, hb3b, hbsq + 4, 128);
  bias_k<<<1, 64, 0, stream>>>(b3h, hb3h, hbsq + 5, 128);
  cvt_k<<<(32768 + 255) / 256, 256, 0, stream>>>(W1b, wb1b, 32768);
  cvt_k<<<(32768 + 255) / 256, 256, 0, stream>>>(W1h, wb1h, 32768);
  cvt_k<<<(98304 + 255) / 256, 256, 0, stream>>>(W2b, wb2b, 98304);
  cvt_k<<<(98304 + 255) / 256, 256, 0, stream>>>(W2h, wb2h, 98304);
  cvt_k<<<(32768 + 255) / 256, 256, 0, stream>>>(W3b, wb3b, 32768);
  cvt_k<<<(32768 + 255) / 256, 256, 0, stream>>>(W3h, wb3h, 32768);

  // ---- layer 1 ----
  agg_k<1><<<grow, 256, 0, stream>>>(S0, nullptr, off_p, lst_p, S1, nullptr, ssq_p1, nullptr, N);
  agg_k<1><<<grow, 256, 0, stream>>>(S0, nullptr, off_n, lst_n, S2, nullptr, ssq_n1, nullptr, N);
  {
    GSrc g{};
    g.p[0] = S1; g.lda[0] = 128; g.ko[0] = 0;
    g.p[1] = S1; g.lda[1] = 128; g.ko[1] = 64;
    g.p[2] = S0; g.lda[2] = 128; g.ko[2] = 0;
    g.p[3] = S0; g.lda[3] = 128; g.ko[3] = 64;
    gemm_bf_k<<<gg1, 256, 0, stream>>>(g, 4, wb1b, 256, F1, 128, N);
    g.p[0] = S2; g.p[1] = S2;
    gemm_bf_k<<<gg1, 256, 0, stream>>>(g, 4, wb1h, 256, F2, 128, N);
  }
  epi_k<2><<<grow, 256, 0, stream>>>(F1, 128, ssq_p1, xsq, nullptr, hb1b, hbsq + 0,
                                     S3, 128, nullptr, 0, hsq_b1, N);
  epi_k<2><<<grow, 256, 0, stream>>>(F2, 128, ssq_n1, xsq, nullptr, hb1h, hbsq + 1,
                                     S4, 128, nullptr, 0, hsq_n1, N);

  // ---- layer 2 aggs: P-list over (hb1,hn1), N-list over (hn1,hb1) ----
  agg_k<2><<<grow, 256, 0, stream>>>(S3, S4, off_p, lst_p, S1, S2, ssq_pp, ssq_np, N);
  agg_k<2><<<grow, 256, 0, stream>>>(S4, S3, off_n, lst_n, S0, S5, ssq_nn, ssq_bn, N);
  {
    GSrc g{};
    // u2b = [A_Pb(S1), A_Nn(S0), hb1(S3)]
    g.p[0] = S1; g.lda[0] = 128; g.ko[0] = 0;
    g.p[1] = S1; g.lda[1] = 128; g.ko[1] = 64;
    g.p[2] = S0; g.lda[2] = 128; g.ko[2] = 0;
    g.p[3] = S0; g.lda[3] = 128; g.ko[3] = 64;
    g.p[4] = S3; g.lda[4] = 128; g.ko[4] = 0;
    g.p[5] = S3; g.lda[5] = 128; g.ko[5] = 64;
    gemm_bf_k<<<gg2, 256, 0, stream>>>(g, 6, wb2b, 384, C3, 256, N);
    // u2n = [A_Pn(S2), A_Nb(S5), hn1(S4)]
    g.p[0] = S2; g.p[1] = S2;
    g.p[2] = S5; g.p[3] = S5;
    g.p[4] = S4; g.p[5] = S4;
    gemm_bf_k<<<gg2, 256, 0, stream>>>(g, 6, wb2h, 384, F1, 256, N);
  }
  epi_k<4><<<grow, 256, 0, stream>>>(C3, 256, ssq_pp, ssq_nn, hsq_b1, hb2b, hbsq + 2,
                                     S0, 256, nullptr, 0, hsq_b2, N);   // hb2 -> S0S1
  epi_k<4><<<grow, 256, 0, stream>>>(F1, 256, ssq_np, ssq_bn, hsq_n1, hb2h, hbsq + 3,
                                     S2, 256, nullptr, 0, hsq_n2, N);   // hn2 -> S2S3

  // ---- layer 3 ----
  {
    GSrc g{};
    g.p[0] = S0; g.lda[0] = 256; g.ko[0] = 0;
    g.p[1] = S0; g.lda[1] = 256; g.ko[1] = 64;
    g.p[2] = S0; g.lda[2] = 256; g.ko[2] = 128;
    g.p[3] = S0; g.lda[3] = 256; g.ko[3] = 192;
    gemm_bf_k<<<gg1, 256, 0, stream>>>(g, 4, wb3b, 256, F1, 128, N);
    g.p[0] = S2; g.p[1] = S2; g.p[2] = S2; g.p[3] = S2;
    gemm_bf_k<<<gg1, 256, 0, stream>>>(g, 4, wb3h, 256, F2, 128, N);
  }
  epi_k<2><<<grow, 256, 0, stream>>>(F1, 128, hsq_b2, nullptr, nullptr, hb3b, hbsq + 4,
                                     nullptr, 0, outf, 3 * D, nullptr, N);
  epi_k<2><<<grow, 256, 0, stream>>>(F2, 128, hsq_n2, nullptr, nullptr, hb3h, hbsq + 5,
                                     nullptr, 0, outf + D, 3 * D, nullptr, N);
  xcopy_k<<<(N * 32 + 255) / 256, 256, 0, stream>>>((const float4*)x, (float4*)d_out, N);
}

// Round 3
// 1103.133 us; speedup vs baseline: 2.0992x; 1.3155x over previous
//
#include <hip/hip_runtime.h>
#include <cstdint>
#include <cstddef>

#define DEV __device__ __forceinline__

typedef unsigned int uint32;
typedef unsigned short ushort16;
typedef __bf16 bfx8 __attribute__((ext_vector_type(8)));
typedef float f32x4 __attribute__((ext_vector_type(4)));

constexpr int D = 128;
constexpr float MINN  = 1e-15f;
constexpr float MAXN  = 1.0f - 4e-3f;   // (1 - BALL_EPS)/sqrt(c), c=1
constexpr float ACLIP = 1.0f - 1e-7f;

DEV float wave_sum(float v) {
#pragma unroll
  for (int off = 32; off > 0; off >>= 1) v += __shfl_xor(v, off, 64);
  return v;
}

DEV float artanh_clip(float x) {   // x >= 0 in all our uses
  x = fminf(x, ACLIP);
  return 0.5f * logf((1.0f + x) / (1.0f - x));
}

DEV ushort16 f2b(float f) {        // fp32 -> bf16 RNE
  uint32 u = __float_as_uint(f);
  u += 0x7fffu + ((u >> 16) & 1u);
  return (ushort16)(u >> 16);
}
DEV float b2f_lo(uint32 v) { return __uint_as_float(v << 16); }
DEV float b2f_hi(uint32 v) { return __uint_as_float(v & 0xffff0000u); }

// ---------------------------------------------------------------- utility
__global__ void zero_k(int* p, int n) {
  int i = blockIdx.x * 256 + threadIdx.x;
  if (i < n) p[i] = 0;
}

__global__ void cvt_k(const float* __restrict__ in, ushort16* __restrict__ out, int n) {
  int i = blockIdx.x * 256 + threadIdx.x;
  if (i < n) out[i] = f2b(in[i]);
}

__global__ void hist_k(const int* __restrict__ dst, int E, int* __restrict__ deg) {
  int i = blockIdx.x * 256 + threadIdx.x;
  if (i < E) atomicAdd(&deg[dst[i]], 1);
}

__global__ __launch_bounds__(1024) void scan1_k(const int* __restrict__ in,
                                                int* __restrict__ out,
                                                int* __restrict__ bsum, int n) {
  __shared__ int sh[1024];
  int t = threadIdx.x;
  int idx = blockIdx.x * 1024 + t;
  int v = (idx < n) ? in[idx] : 0;
  sh[t] = v;
  __syncthreads();
  for (int o = 1; o < 1024; o <<= 1) {
    int add = (t >= o) ? sh[t - o] : 0;
    __syncthreads();
    sh[t] += add;
    __syncthreads();
  }
  if (idx < n) out[idx] = sh[t] - v;     // exclusive
  if (t == 1023) bsum[blockIdx.x] = sh[t];
}

__global__ void scan2_k(const int* __restrict__ bsum, int* __restrict__ boff, int nb) {
  if (threadIdx.x == 0 && blockIdx.x == 0) {
    int run = 0;
    for (int b = 0; b < nb; ++b) { boff[b] = run; run += bsum[b]; }
  }
}

__global__ void scan3_k(int* __restrict__ off, const int* __restrict__ boff,
                        int* __restrict__ cur, int n, int E) {
  int idx = blockIdx.x * 256 + threadIdx.x;
  if (idx < n) {
    int v = off[idx] + boff[idx >> 10];
    off[idx] = v;
    cur[idx] = v;
  }
  if (idx == 0) off[n] = E;
}

// XCD-partitioned CSR fill: block b owns dst-range b%8 (round-robin -> XCD b%8),
// so each lst/cur range stays in ONE XCD's L2 -> one writeback per line.
__global__ __launch_bounds__(256) void fill_part_k(
    const int* __restrict__ src, const int* __restrict__ dst, int E,
    int* __restrict__ cur, int* __restrict__ lst, int rngsz, int chunkE) {
  const int r = blockIdx.x & 7;
  const int chunk = blockIdx.x >> 3;
  const unsigned lo = (unsigned)(r * rngsz);
  const int base = chunk * chunkE;
  const int end = min(base + chunkE, E);
  for (int i = base + (int)threadIdx.x; i < end; i += 256) {
    int d = dst[i];
    if ((unsigned)d - lo < (unsigned)rngsz) {
      int p = atomicAdd(&cur[d], 1);
      lst[p] = src[i];
    }
  }
}

// x -> xsq (rowsumsq) + bf16 copy
__global__ void rowsq_k(const float* __restrict__ x, float* __restrict__ out,
                        ushort16* __restrict__ xb, int n) {
  int lane = threadIdx.x & 63;
  int row = blockIdx.x * 4 + (threadIdx.x >> 6);
  if (row >= n) return;
  const float2 v = *(const float2*)(x + (size_t)row * D + lane * 2);
  uint32 pk = (uint32)f2b(v.x) | ((uint32)f2b(v.y) << 16);
  *(uint32*)(xb + (size_t)row * D + lane * 2) = pk;
  float s = wave_sum(v.x * v.x + v.y * v.y);
  if (lane == 0) out[row] = s;
}

// hb = proj(expmap0(b)), hbsq = ||hb||^2.  one wave.
__global__ void bias_k(const float* __restrict__ b, float* __restrict__ hb,
                       float* __restrict__ hbsq, int dim) {
  int lane = threadIdx.x;
  int ne = dim / 64;
  float v[4];
  float ssq = 0.0f;
  for (int e = 0; e < ne; ++e) { v[e] = b[e * 64 + lane]; ssq += v[e] * v[e]; }
  ssq = wave_sum(ssq);
  float nr = sqrtf(ssq);
  float nc = fmaxf(nr, MINN);
  float es = tanhf(nc) / nc;
  float on = es * nr;
  float f = (on > MAXN) ? (MAXN / fmaxf(on, MINN)) : 1.0f;
  float w = es * f;
  float osq = 0.0f;
  for (int e = 0; e < ne; ++e) { v[e] *= w; osq += v[e] * v[e]; hb[e * 64 + lane] = v[e]; }
  osq = wave_sum(osq);
  if (lane == 0) *hbsq = osq;
}

// mean aggregation over CSR bucket (bf16 in, bf16 out + fp32 rowsumsq of mean)
template <int NF>
__global__ __launch_bounds__(256) void agg_k(
    const ushort16* __restrict__ F0, const ushort16* __restrict__ F1,
    const int* __restrict__ off, const int* __restrict__ lst,
    ushort16* __restrict__ O0, ushort16* __restrict__ O1,
    float* __restrict__ S0, float* __restrict__ S1, int n) {
  int lane = threadIdx.x & 63;
  int row = blockIdx.x * 4 + (threadIdx.x >> 6);
  if (row >= n) return;
  int j0 = off[row], j1 = off[row + 1];
  float a0 = 0, b0 = 0, a1 = 0, b1 = 0;
  int j = j0;
  for (; j + 1 < j1; j += 2) {
    int sa = lst[j], sb = lst[j + 1];
    uint32 u0 = *(const uint32*)(F0 + (size_t)sa * D + lane * 2);
    uint32 u1 = *(const uint32*)(F0 + (size_t)sb * D + lane * 2);
    a0 += b2f_lo(u0) + b2f_lo(u1); b0 += b2f_hi(u0) + b2f_hi(u1);
    if (NF == 2) {
      uint32 w0 = *(const uint32*)(F1 + (size_t)sa * D + lane * 2);
      uint32 w1 = *(const uint32*)(F1 + (size_t)sb * D + lane * 2);
      a1 += b2f_lo(w0) + b2f_lo(w1); b1 += b2f_hi(w0) + b2f_hi(w1);
    }
  }
  if (j < j1) {
    int sa = lst[j];
    uint32 u0 = *(const uint32*)(F0 + (size_t)sa * D + lane * 2);
    a0 += b2f_lo(u0); b0 += b2f_hi(u0);
    if (NF == 2) {
      uint32 w0 = *(const uint32*)(F1 + (size_t)sa * D + lane * 2);
      a1 += b2f_lo(w0); b1 += b2f_hi(w0);
    }
  }
  float inv = 1.0f / fmaxf((float)(j1 - j0), 1.0f);
  a0 *= inv; b0 *= inv;
  float s = wave_sum(a0 * a0 + b0 * b0);
  *(uint32*)(O0 + (size_t)row * D + lane * 2) = (uint32)f2b(a0) | ((uint32)f2b(b0) << 16);
  if (lane == 0) S0[row] = s;
  if (NF == 2) {
    a1 *= inv; b1 *= inv;
    float s1 = wave_sum(a1 * a1 + b1 * b1);
    *(uint32*)(O1 + (size_t)row * D + lane * 2) = (uint32)f2b(a1) | ((uint32)f2b(b1) << 16);
    if (lane == 0) S1[row] = s1;
  }
}

// ------------------------------------------------ fused bf16 MFMA GEMM + hyperbolic epilogue
// Block: 64 rows x full dout (NCT col-tiles of 16 per wave; dout = 64*NCT/... = 4 waves * NCT*16).
// After GEMM: round A reduces (||mx||^2, <mx,hb>) per row; scalar chain gives
// c1 = scal*ax, c2 = ay, la; round B reduces sum(max(p,0)^2); scalar gives g = w*la;
// out = g*max(c1*mx + c2*hb, 0).
struct GSrc {
  const ushort16* p[6];
  int lda[6];
  int ko[6];
};

template <int NCT>   // 2 -> dout=128, 4 -> dout=256
__global__ __launch_bounds__(256) void gemm_epi_k(
    GSrc ga, int nchunk, const ushort16* __restrict__ W, int ldw,
    const float* __restrict__ xs0, const float* __restrict__ xs1,
    const float* __restrict__ xs2,
    const float* __restrict__ hb, const float* __restrict__ hbsq_p,
    ushort16* __restrict__ outb, int ldob,
    float* __restrict__ outf, int ldof, int ocol,
    float* __restrict__ hsq_out, int M) {
  constexpr int DOUT = NCT * 64;
  __shared__ ushort16 As[64 * 64];           // 8 KB
  __shared__ ushort16 Bs[DOUT * 64];         // 16/32 KB
  __shared__ float hbs[DOUT];
  __shared__ float redA[4][64][2];
  __shared__ float redB[4][64];
  __shared__ float rs[64][4];                // c1, c2, la, g
  const int t = threadIdx.x;
  const int l = t & 63;
  const int w = t >> 6;
  const int brow = blockIdx.x * 64;
  const int sr = t >> 3;   // 0..31
  const int sc = t & 7;
  for (int c = t; c < DOUT; c += 256) hbs[c] = hb[c];
  f32x4 acc[4][NCT] = {};
  for (int c = 0; c < nchunk; ++c) {
    const ushort16* S = ga.p[c];
    const int lda = ga.lda[c];
    const int ko = ga.ko[c];
#pragma unroll
    for (int h = 0; h < 2; ++h) {            // A: 64 rows x 64 k
      int row = sr + h * 32;
      int gr = brow + row;
      uint4 v = make_uint4(0, 0, 0, 0);
      if (gr < M) v = *(const uint4*)(S + (size_t)gr * lda + ko + sc * 8);
      *(uint4*)((char*)As + row * 128 + ((sc * 16) ^ ((row & 7) << 4))) = v;
    }
#pragma unroll
    for (int h = 0; h < NCT * 2; ++h) {      // B: DOUT outcols x 64 k
      int u = t + h * 256;
      int row = u >> 3;
      int cc = u & 7;
      uint4 v = *(const uint4*)(W + (size_t)row * ldw + c * 64 + cc * 8);
      *(uint4*)((char*)Bs + row * 128 + ((cc * 16) ^ ((row & 7) << 4))) = v;
    }
    __syncthreads();
#pragma unroll
    for (int ks = 0; ks < 2; ++ks) {
      const int kb = ks * 64 + (l >> 4) * 16;
      bfx8 a[4], b[NCT];
#pragma unroll
      for (int i = 0; i < 4; ++i) {
        int row = i * 16 + (l & 15);
        a[i] = *(const bfx8*)((const char*)As + row * 128 + (kb ^ ((row & 7) << 4)));
      }
#pragma unroll
      for (int j = 0; j < NCT; ++j) {
        int row = w * (NCT * 16) + j * 16 + (l & 15);
        b[j] = *(const bfx8*)((const char*)Bs + row * 128 + (kb ^ ((row & 7) << 4)));
      }
#pragma unroll
      for (int i = 0; i < 4; ++i)
#pragma unroll
        for (int j = 0; j < NCT; ++j)
          acc[i][j] = __builtin_amdgcn_mfma_f32_16x16x32_bf16(a[i], b[j], acc[i][j], 0, 0, 0);
    }
    __syncthreads();
  }

  // ---- round A: per-row (ssq, xy) ----
#pragma unroll
  for (int i = 0; i < 4; ++i)
#pragma unroll
    for (int r = 0; r < 4; ++r) {
      float s = 0.0f, xy = 0.0f;
#pragma unroll
      for (int j = 0; j < NCT; ++j) {
        float m = acc[i][j][r];
        int col = w * (NCT * 16) + j * 16 + (l & 15);
        s += m * m;
        xy += m * hbs[col];
      }
#pragma unroll
      for (int off = 1; off < 16; off <<= 1) {
        s += __shfl_xor(s, off, 64);
        xy += __shfl_xor(xy, off, 64);
      }
      if ((l & 15) == 0) {
        int row = i * 16 + (l >> 4) * 4 + r;
        redA[w][row][0] = s;
        redA[w][row][1] = xy;
      }
    }
  __syncthreads();

  // ---- scalar phase 1 ----
  if (t < 64 && brow + t < M) {
    float ssq = redA[0][t][0] + redA[1][t][0] + redA[2][t][0] + redA[3][t][0];
    float xyr = redA[0][t][1] + redA[1][t][1] + redA[2][t][1] + redA[3][t][1];
    float mxn_raw = sqrtf(ssq);
    float xnsq = xs0[brow + t];
    if (xs1) xnsq += xs1[brow + t];
    if (xs2) xnsq += xs2[brow + t];
    float xn = fmaxf(sqrtf(xnsq), MINN);
    float mxn = fmaxf(mxn_raw, MINN);
    float scal = tanhf(mxn / xn * artanh_clip(xn)) / mxn;
    float rn_raw = scal * mxn_raw;
    if (rn_raw > MAXN) { scal *= MAXN / fmaxf(rn_raw, MINN); rn_raw = MAXN; }
    float xyv = scal * xyr;
    float x2 = rn_raw * rn_raw;
    float y2 = *hbsq_p;
    float den = fmaxf(1.0f + 2.0f * xyv + x2 * y2, MINN);
    float ax = (1.0f + 2.0f * xyv + y2) / den;
    float ay = (1.0f - x2) / den;
    float vsq = scal * scal * ssq;
    float psq = fmaxf(ax * ax * vsq + 2.0f * ax * ay * xyv + ay * ay * y2, 0.0f);
    float pn_raw = sqrtf(psq);
    float f2s = (pn_raw > MAXN) ? (MAXN / fmaxf(pn_raw, MINN)) : 1.0f;
    pn_raw = fminf(pn_raw, MAXN);
    float pn = fmaxf(pn_raw, MINN);
    float la = artanh_clip(pn) / pn * f2s;
    rs[t][0] = scal * ax;
    rs[t][1] = ay;
    rs[t][2] = la;
  }
  __syncthreads();

  // ---- round B: p = c1*mx + c2*hb; ppos = sum(max(p,0)^2) ----
#pragma unroll
  for (int i = 0; i < 4; ++i)
#pragma unroll
    for (int r = 0; r < 4; ++r) {
      int row = i * 16 + (l >> 4) * 4 + r;
      float c1 = rs[row][0], c2 = rs[row][1];
      float pp = 0.0f;
#pragma unroll
      for (int j = 0; j < NCT; ++j) {
        int col = w * (NCT * 16) + j * 16 + (l & 15);
        float p = c1 * acc[i][j][r] + c2 * hbs[col];
        p = fmaxf(p, 0.0f);
        acc[i][j][r] = p;
        pp += p * p;
      }
#pragma unroll
      for (int off = 1; off < 16; off <<= 1) pp += __shfl_xor(pp, off, 64);
      if ((l & 15) == 0) redB[w][row] = pp;
    }
  __syncthreads();

  // ---- scalar phase 2 ----
  if (t < 64 && brow + t < M) {
    float ppos = redB[0][t] + redB[1][t] + redB[2][t] + redB[3][t];
    float la = rs[t][2];
    float tsq = la * la * ppos;
    float tn_raw = sqrtf(tsq);
    float tnc = fmaxf(tn_raw, MINN);
    float es = tanhf(tnc) / tnc;
    float on_raw = es * tn_raw;
    float f3 = (on_raw > MAXN) ? (MAXN / fmaxf(on_raw, MINN)) : 1.0f;
    float wsc = es * f3;
    float g = wsc * la;
    rs[t][3] = g;
    if (hsq_out) hsq_out[brow + t] = g * g * ppos;
  }
  __syncthreads();

  // ---- write out = g * relu(p) ----
#pragma unroll
  for (int i = 0; i < 4; ++i)
#pragma unroll
    for (int r = 0; r < 4; ++r) {
      int row = i * 16 + (l >> 4) * 4 + r;
      int gr = brow + row;
      if (gr < M) {
        float g = rs[row][3];
#pragma unroll
        for (int j = 0; j < NCT; ++j) {
          int col = w * (NCT * 16) + j * 16 + (l & 15);
          float o = g * acc[i][j][r];
          if (outb) outb[(size_t)gr * ldob + col] = f2b(o);
          else outf[(size_t)gr * ldof + ocol + col] = o;
        }
      }
    }
}

__global__ void xcopy_k(const float4* __restrict__ x4, float4* __restrict__ out4, int n) {
  int gid = blockIdx.x * 256 + threadIdx.x;
  if (gid < n * 32) {
    int i = gid >> 5, q = gid & 31;
    out4[(size_t)i * 96 + 64 + q] = x4[(size_t)i * 32 + q];
  }
}

// ---------------------------------------------------------------- launcher
extern "C" void kernel_launch(void* const* d_in, const int* in_sizes, int n_in,
                              void* d_out, int out_size, void* d_ws, size_t ws_size,
                              hipStream_t stream) {
  const float* x = (const float*)d_in[0];
  const int* src_pos = (const int*)d_in[1];
  const int* dst_pos = (const int*)d_in[2];
  const int* src_neg = (const int*)d_in[3];
  const int* dst_neg = (const int*)d_in[4];
  const float* W1b = (const float*)d_in[5];
  const float* b1b = (const float*)d_in[6];
  const float* W1h = (const float*)d_in[7];
  const float* b1h = (const float*)d_in[8];
  const float* W2b = (const float*)d_in[9];
  const float* b2b = (const float*)d_in[10];
  const float* W2h = (const float*)d_in[11];
  const float* b2h = (const float*)d_in[12];
  const float* W3b = (const float*)d_in[13];
  const float* b3b = (const float*)d_in[14];
  const float* W3h = (const float*)d_in[15];
  const float* b3h = (const float*)d_in[16];

  const int N = in_sizes[0] / D;   // 100000
  const int E = in_sizes[1];       // 1600000

  // ---- workspace: ints | fp32 | bf16 ----
  int* iw = (int*)d_ws;
  size_t io = 0;
  int* degi_p = iw + io; io += N;
  int* degi_n = iw + io; io += N;
  int* off_p = iw + io;  io += N + 1;
  int* off_n = iw + io;  io += N + 1;
  int* cur_p = iw + io;  io += N;
  int* cur_n = iw + io;  io += N;
  int* bsum_p = iw + io; io += 128;
  int* boff_p = iw + io; io += 128;
  int* bsum_n = iw + io; io += 128;
  int* boff_n = iw + io; io += 128;
  int* lst_p = iw + io;  io += E;
  int* lst_n = iw + io;  io += E;
  io = (io + 63) & ~(size_t)63;

  float* fw = (float*)(iw + io);
  size_t fo = 0;
  float* xsq = fw + fo;    fo += N;
  float* hsq_b1 = fw + fo; fo += N;
  float* hsq_n1 = fw + fo; fo += N;
  float* hsq_b2 = fw + fo; fo += N;
  float* hsq_n2 = fw + fo; fo += N;
  float* ssq_p1 = fw + fo; fo += N;
  float* ssq_n1 = fw + fo; fo += N;
  float* ssq_pp = fw + fo; fo += N;   // ||A_P(hb1)||^2
  float* ssq_np = fw + fo; fo += N;   // ||A_P(hn1)||^2
  float* ssq_nn = fw + fo; fo += N;   // ||A_N(hn1)||^2
  float* ssq_bn = fw + fo; fo += N;   // ||A_N(hb1)||^2
  float* hbase = fw + fo;  fo += 1056;
  fo = (fo + 31) & ~(size_t)31;

  ushort16* SB = (ushort16*)(fw + fo);
  const size_t NSB = (size_t)N * D;
  ushort16* S0 = SB;             // xb -> A_N(hn1) -> hn2(lo)
  ushort16* S1 = SB + NSB;       // A_P(x) -> A_P(hb1) -> hn2(hi)
  ushort16* S2 = SB + 2 * NSB;   // A_N(x) -> A_P(hn1)
  ushort16* S3 = SB + 3 * NSB;   // hb1
  ushort16* S4 = SB + 4 * NSB;   // hn1
  ushort16* S5 = SB + 5 * NSB;   // A_N(hb1)
  ushort16* S6 = SB + 6 * NSB;   // hb2(lo)
  ushort16* S7 = SB + 7 * NSB;   // hb2(hi)
  ushort16* wb1b = SB + 8 * NSB;
  ushort16* wb1h = wb1b + 32768;
  ushort16* wb2b = wb1h + 32768;
  ushort16* wb2h = wb2b + 98304;
  ushort16* wb3b = wb2h + 98304;
  ushort16* wb3h = wb3b + 32768;

  float* outf = (float*)d_out;

  float* hb1b = hbase + 0;
  float* hb1h = hbase + 128;
  float* hb2b = hbase + 256;
  float* hb2h = hbase + 512;
  float* hb3b = hbase + 768;
  float* hb3h = hbase + 896;
  float* hbsq = hbase + 1024;

  const int nb = (N + 1023) / 1024;
  const int grow = (N + 3) / 4;
  const int geb = (E + 255) / 256;
  const int gf = (N + 63) / 64;        // fused gemm+epi blocks
  const int rngsz = (N + 7) / 8;
  const int chunkE = (E + 255) / 256;  // 256 chunks
  const int gfill = 256 * 8;

  // ---- CSR build ----
  zero_k<<<(2 * N + 255) / 256, 256, 0, stream>>>(degi_p, 2 * N);
  hist_k<<<geb, 256, 0, stream>>>(dst_pos, E, degi_p);
  hist_k<<<geb, 256, 0, stream>>>(dst_neg, E, degi_n);
  scan1_k<<<nb, 1024, 0, stream>>>(degi_p, off_p, bsum_p, N);
  scan1_k<<<nb, 1024, 0, stream>>>(degi_n, off_n, bsum_n, N);
  scan2_k<<<1, 64, 0, stream>>>(bsum_p, boff_p, nb);
  scan2_k<<<1, 64, 0, stream>>>(bsum_n, boff_n, nb);
  scan3_k<<<(N + 255) / 256, 256, 0, stream>>>(off_p, boff_p, cur_p, N, E);
  scan3_k<<<(N + 255) / 256, 256, 0, stream>>>(off_n, boff_n, cur_n, N, E);
  fill_part_k<<<gfill, 256, 0, stream>>>(src_pos, dst_pos, E, cur_p, lst_p, rngsz, chunkE);
  fill_part_k<<<gfill, 256, 0, stream>>>(src_neg, dst_neg, E, cur_n, lst_n, rngsz, chunkE);

  // ---- constants ----
  rowsq_k<<<grow, 256, 0, stream>>>(x, xsq, S0, N);
  bias_k<<<1, 64, 0, stream>>>(b1b, hb1b, hbsq + 0, 128);
  bias_k<<<1, 64, 0, stream>>>(b1h, hb1h, hbsq + 1, 128);
  bias_k<<<1, 64, 0, stream>>>(b2b, hb2b, hbsq + 2, 256);
  bias_k<<<1, 64, 0, stream>>>(b2h, hb2h, hbsq + 3, 256);
  bias_k<<<1, 64, 0, stream>>>(b3b, hb3b, hbsq + 4, 128);
  bias_k<<<1, 64, 0, stream>>>(b3h, hb3h, hbsq + 5, 128);
  cvt_k<<<(32768 + 255) / 256, 256, 0, stream>>>(W1b, wb1b, 32768);
  cvt_k<<<(32768 + 255) / 256, 256, 0, stream>>>(W1h, wb1h, 32768);
  cvt_k<<<(98304 + 255) / 256, 256, 0, stream>>>(W2b, wb2b, 98304);
  cvt_k<<<(98304 + 255) / 256, 256, 0, stream>>>(W2h, wb2h, 98304);
  cvt_k<<<(32768 + 255) / 256, 256, 0, stream>>>(W3b, wb3b, 32768);
  cvt_k<<<(32768 + 255) / 256, 256, 0, stream>>>(W3h, wb3h, 32768);

  // ---- layer 1 ----
  agg_k<1><<<grow, 256, 0, stream>>>(S0, nullptr, off_p, lst_p, S1, nullptr, ssq_p1, nullptr, N);
  agg_k<1><<<grow, 256, 0, stream>>>(S0, nullptr, off_n, lst_n, S2, nullptr, ssq_n1, nullptr, N);
  {
    GSrc g{};
    g.p[0] = S1; g.lda[0] = 128; g.ko[0] = 0;
    g.p[1] = S1; g.lda[1] = 128; g.ko[1] = 64;
    g.p[2] = S0; g.lda[2] = 128; g.ko[2] = 0;
    g.p[3] = S0; g.lda[3] = 128; g.ko[3] = 64;
    gemm_epi_k<2><<<gf, 256, 0, stream>>>(g, 4, wb1b, 256, ssq_p1, xsq, nullptr,
        hb1b, hbsq + 0, S3, 128, nullptr, 0, 0, hsq_b1, N);
    g.p[0] = S2; g.p[1] = S2;
    gemm_epi_k<2><<<gf, 256, 0, stream>>>(g, 4, wb1h, 256, ssq_n1, xsq, nullptr,
        hb1h, hbsq + 1, S4, 128, nullptr, 0, 0, hsq_n1, N);
  }

  // ---- layer 2 aggs: P-list over (hb1,hn1), N-list over (hn1,hb1) ----
  agg_k<2><<<grow, 256, 0, stream>>>(S3, S4, off_p, lst_p, S1, S2, ssq_pp, ssq_np, N);
  agg_k<2><<<grow, 256, 0, stream>>>(S4, S3, off_n, lst_n, S0, S5, ssq_nn, ssq_bn, N);
  {
    GSrc g{};
    // u2b = [A_P(hb1)=S1, A_N(hn1)=S0, hb1=S3] -> hb2 in S6S7
    g.p[0] = S1; g.lda[0] = 128; g.ko[0] = 0;
    g.p[1] = S1; g.lda[1] = 128; g.ko[1] = 64;
    g.p[2] = S0; g.lda[2] = 128; g.ko[2] = 0;
    g.p[3] = S0; g.lda[3] = 128; g.ko[3] = 64;
    g.p[4] = S3; g.lda[4] = 128; g.ko[4] = 0;
    g.p[5] = S3; g.lda[5] = 128; g.ko[5] = 64;
    gemm_epi_k<4><<<gf, 256, 0, stream>>>(g, 6, wb2b, 384, ssq_pp, ssq_nn, hsq_b1,
        hb2b, hbsq + 2, S6, 256, nullptr, 0, 0, hsq_b2, N);
    // u2n = [A_P(hn1)=S2, A_N(hb1)=S5, hn1=S4] -> hn2 in S0S1 (dead inputs)
    g.p[0] = S2; g.p[1] = S2;
    g.p[2] = S5; g.p[3] = S5;
    g.p[4] = S4; g.p[5] = S4;
    gemm_epi_k<4><<<gf, 256, 0, stream>>>(g, 6, wb2h, 384, ssq_np, ssq_bn, hsq_n1,
        hb2h, hbsq + 3, S0, 256, nullptr, 0, 0, hsq_n2, N);
  }

  // ---- layer 3: hb2 = S6 (lda 256), hn2 = S0 (lda 256) -> d_out fp32 ----
  {
    GSrc g{};
    g.p[0] = S6; g.lda[0] = 256; g.ko[0] = 0;
    g.p[1] = S6; g.lda[1] = 256; g.ko[1] = 64;
    g.p[2] = S6; g.lda[2] = 256; g.ko[2] = 128;
    g.p[3] = S6; g.lda[3] = 256; g.ko[3] = 192;
    gemm_epi_k<2><<<gf, 256, 0, stream>>>(g, 4, wb3b, 256, hsq_b2, nullptr, nullptr,
        hb3b, hbsq + 4, nullptr, 0, outf, 3 * D, 0, nullptr, N);
    g.p[0] = S0; g.p[1] = S0; g.p[2] = S0; g.p[3] = S0;
    gemm_epi_k<2><<<gf, 256, 0, stream>>>(g, 4, wb3h, 256, hsq_n2, nullptr, nullptr,
        hb3h, hbsq + 5, nullptr, 0, outf, 3 * D, 128, nullptr, N);
  }
  xcopy_k<<<(N * 32 + 255) / 256, 256, 0, stream>>>((const float4*)x, (float4*)d_out, N);
}